// Round 1
// 36204.660 us; speedup vs baseline: 1.3128x; 1.3128x over previous
//
#include <hip/hip_runtime.h>
#include <math.h>
#include <float.h>

// Problem: B=256, H=1024, I=1, O=512, T=512. Autoregressive LSTM + greedy head.
#define NB 256
#define NH 1024
#define NO 512
#define NT 512

// ---------------- workspace layout (float offsets) ----------------
// hT4 layout: [q=u>>2][b][j=u&3]  (256K floats per buffer)
#define OFF_HT4_0 0
#define OFF_HT4_1 (256*1024)
#define OFF_CT    (2*256*1024)            // cT [u][b]
#define OFF_WLT   (3*256*1024)            // packed w_lin: [u/4][o][4] = 512K floats
#define OFF_PART  (OFF_WLT + 512*1024)    // argmax partials [B][16][{val,idx}] = 8192
#define OFF_BAR   (OFF_PART + 8192)       // grid barrier: cnt @ +0, gen @ +32

__device__ __forceinline__ float sigf(float x) { return 1.f / (1.f + expf(-x)); }

#define FMA4(A, W, H4) \
  A = fmaf((W).x, (H4).x, A); A = fmaf((W).y, (H4).y, A); \
  A = fmaf((W).z, (H4).z, A); A = fmaf((W).w, (H4).w, A);

// ---------------------------------------------------------------------------
// Init: pack h0=z into hT4 ping, c=0, pack w_lin into [u/4][o][4] (so head
// weight loads are coalesced float4), seed argmax partials to (-FLT_MAX, 0)
// so step 0 sees xin = 0, zero the grid barrier.
// ---------------------------------------------------------------------------
__global__ void k_init(const float* __restrict__ z, const float* __restrict__ w_lin,
                       float* __restrict__ ws) {
  int idx = blockIdx.x * 256 + threadIdx.x;
  if (idx < 512 * 1024) {                 // wltp[uq*2048 + o*4 + j] = w_lin[o][4uq+j]
    int j = idx & 3, o = (idx >> 2) & 511, uq = idx >> 11;
    ws[OFF_WLT + idx] = w_lin[o * 1024 + (uq << 2) + j];
  }
  if (idx < 256 * 1024) {                 // hT4[q][b][j] = z[b][4q+j]; cT = 0
    int q = idx >> 10, r = idx & 1023, b = r >> 2, j = r & 3;
    ws[OFF_HT4_0 + idx] = z[b * 1024 + (q << 2) + j];
    ws[OFF_CT + idx] = 0.f;
  }
  if (idx < 8192) ws[OFF_PART + idx] = (idx & 1) ? 0.f : -FLT_MAX;
  if (idx < 64) ((unsigned*)(ws + OFF_BAR))[idx] = 0u;
}

// ---------------------------------------------------------------------------
// Device-scope grid barrier (generation/sense counter). Requires all 256
// blocks co-resident -> launched via hipLaunchCooperativeKernel.
// Release: ACQ_REL RMW on cnt (each thread's stores already drained by the
// compiler's waitcnt before s_barrier in __syncthreads; the RMW's release
// writes back the XCD L2). Acquire: fence after spin (invalidates L1/L2 so
// every thread in the block sees remote writes).
// ---------------------------------------------------------------------------
__device__ __forceinline__ void gbar(unsigned* bar) {
  __syncthreads();
  if (threadIdx.x == 0) {
    unsigned* cnt = bar;
    unsigned* gen = bar + 32;
    unsigned g = __hip_atomic_load(gen, __ATOMIC_RELAXED, __HIP_MEMORY_SCOPE_AGENT);
    unsigned a = __hip_atomic_fetch_add(cnt, 1u, __ATOMIC_ACQ_REL, __HIP_MEMORY_SCOPE_AGENT);
    if (a == 255u) {
      __hip_atomic_store(cnt, 0u, __ATOMIC_RELAXED, __HIP_MEMORY_SCOPE_AGENT);
      __hip_atomic_fetch_add(gen, 1u, __ATOMIC_RELEASE, __HIP_MEMORY_SCOPE_AGENT);
    } else {
      while (__hip_atomic_load(gen, __ATOMIC_RELAXED, __HIP_MEMORY_SCOPE_AGENT) == g)
        __builtin_amdgcn_s_sleep(2);
      __builtin_amdgcn_fence(__ATOMIC_ACQUIRE, "agent");
    }
  }
  __syncthreads();
}

// ---------------------------------------------------------------------------
// Persistent kernel: all 512 timesteps. 256 blocks x 512 threads (8 waves,
// 2 waves/SIMD). Block owns units u0=blk*4..+3 (16 gate rows, 64KB w_hh in
// LDS, staged ONCE). Per step:
//   phase G: wave (rg=wid&1, kh=wid>>1): 8 rows x 4 batch-cols x K-quarter.
//            Each register-held w row feeds 16 FMAs -> global h traffic
//            2MB/CU/step (vs 4MB baseline), lockstep s_barrier for L1 reuse.
//            K-partials summed via LDS; cell update on all 512 threads.
//   phase H: block = (16 batches x 32 outputs); h tile in LDS; K split 8-ways
//            across waves (wlt float4 coalesced, no duplicate streams); LDS
//            reduce; shfl argmax (first-index tie-break) -> partial per chunk.
// 2 grid barriers/step (G->H needs full h; H->G' needs full argmax).
// ---------------------------------------------------------------------------
__global__ __launch_bounds__(512, 2) void k_persist(
    const float* __restrict__ w_hh, const float* __restrict__ w_ih,
    const float* __restrict__ b_ih, const float* __restrict__ b_hh,
    const float* __restrict__ b_lin, float* __restrict__ out,
    float* __restrict__ ws) {
  __shared__ float wlds[16 * 1024];   // resident w_hh rows (64 KB)
  __shared__ float sh[16 * 1028];     // G: k-split gate xch (64KB) / H: h tile (padded)
  __shared__ float xpart[8 * 512];    // H: k-split output partials (16 KB)

  const int tid = threadIdx.x;
  const int blk = blockIdx.x;
  const int lane = tid & 63;
  const int wid = tid >> 6;           // wave 0..7
  const int rg = wid & 1;             // row-group: rows rg*8 .. rg*8+7
  const int kh = wid >> 1;            // k-quarter: k in [kh*256, kh*256+256)

  unsigned* bar = (unsigned*)(ws + OFF_BAR);
  float* part = ws + OFF_PART;
  float* cT = ws + OFF_CT;
  const float* wlt = ws + OFF_WLT;

  // ---- one-time: stage 16 w_hh rows (row r=uu*4+g <-> global g*1024+blk*4+uu)
#pragma unroll
  for (int i = 0; i < 8; ++i) {
    int idx = (i << 9) + tid;         // 0..4095 float4s
    int r = idx >> 8, c4 = idx & 255;
    int grow = ((r & 3) << 10) + (blk << 2) + (r >> 2);
    *(float4*)(&wlds[(r << 10) + (c4 << 2)]) =
        *(const float4*)(w_hh + (grow << 10) + (c4 << 2));
  }

  // ---- per-thread constants: gates epilogue handles (unit ue, batches be,be+1)
  const int uue = tid >> 7;
  const int ue = (blk << 2) + uue;
  const float bi_ = b_ih[ue] + b_hh[ue];
  const float bf_ = b_ih[1024 + ue] + b_hh[1024 + ue];
  const float bg_ = b_ih[2048 + ue] + b_hh[2048 + ue];
  const float bo_ = b_ih[3072 + ue] + b_hh[3072 + ue];
  const float wi_ = w_ih[ue], wf_ = w_ih[1024 + ue];
  const float wg_ = w_ih[2048 + ue], wo_ = w_ih[3072 + ue];
  const int be = (tid << 1) & 255;

  // ---- head constants: block = (bc = blk>>4 -> 16 batches, oc = blk&15 -> 32 o's)
  const int oc = blk & 15, bc = blk >> 4;
  const int oo = (oc << 5) + (tid & 31);   // output-mapping o (after reduction)
  const int ob = (bc << 4) + (tid >> 5);   // output-mapping b
  const float blr = b_lin[oo];
  float* outp = out + ob * (NT * NO) + oo;
  const int ow = (oc << 5) + (lane & 31);  // compute-mapping o (k-split)
  const int hb = (lane >> 5) << 3;         // compute bi base: 0 or 8
  const float* wpH = wlt + ((wid << 5) << 11) + (ow << 2);  // wave's u-range base

  __syncthreads();

  for (int t = 0; t < NT; ++t) {
    const float* hin = ws + ((t & 1) ? OFF_HT4_1 : OFF_HT4_0);
    float* hout = ws + ((t & 1) ? OFF_HT4_0 : OFF_HT4_1);

    // ================= phase G: gates = h @ w_hh^T =================
    float acc[8][4];
#pragma unroll
    for (int j = 0; j < 8; ++j)
#pragma unroll
      for (int bb = 0; bb < 4; ++bb) acc[j][bb] = 0.f;

    const float* hq = hin + (kh << 16) + (lane << 2);
    const float* wb = &wlds[((rg << 3) << 10) + (kh << 8)];

    float4 hA[4], hB[4];
#pragma unroll
    for (int bb = 0; bb < 4; ++bb) hA[bb] = *(const float4*)(hq + (bb << 8));

    for (int qg = 0; qg < 64; qg += 2) {
      if ((qg & 3) == 0) __builtin_amdgcn_s_barrier();  // wave lockstep -> L1 reuse
#pragma unroll
      for (int bb = 0; bb < 4; ++bb)
        hB[bb] = *(const float4*)(hq + ((qg + 1) << 10) + (bb << 8));
#pragma unroll
      for (int j = 0; j < 8; ++j) {
        const float4 wv = *(const float4*)(wb + (j << 10) + (qg << 2));
#pragma unroll
        for (int bb = 0; bb < 4; ++bb) { FMA4(acc[j][bb], wv, hA[bb]); }
      }
      if (qg + 2 < 64) {
#pragma unroll
        for (int bb = 0; bb < 4; ++bb)
          hA[bb] = *(const float4*)(hq + ((qg + 2) << 10) + (bb << 8));
      }
#pragma unroll
      for (int j = 0; j < 8; ++j) {
        const float4 wv = *(const float4*)(wb + (j << 10) + ((qg + 1) << 2));
#pragma unroll
        for (int bb = 0; bb < 4; ++bb) { FMA4(acc[j][bb], wv, hB[bb]); }
      }
    }

    // exchange k-quarter partials via LDS: sh[kh][row(0..15)][b]
#pragma unroll
    for (int j = 0; j < 8; ++j)
#pragma unroll
      for (int bb = 0; bb < 4; ++bb)
        sh[(kh << 12) + (((rg << 3) + j) << 8) + lane + (bb << 6)] = acc[j][bb];
    __syncthreads();

    // epilogue: 2 (unit,b) cell updates per thread (b = be, be+1)
#pragma unroll
    for (int pp = 0; pp < 2; ++pp) {
      const int b = be + pp;
      // combine 16 argmax partials (ascending o-chunk, strict > => first wins)
      const float* pb = part + (b << 5);
      float4 p = *(const float4*)(pb);
      float v = p.x, ix = p.y;
      if (p.z > v) { v = p.z; ix = p.w; }
#pragma unroll
      for (int cc = 1; cc < 8; ++cc) {
        float4 p2 = *(const float4*)(pb + (cc << 2));
        if (p2.x > v) { v = p2.x; ix = p2.y; }
        if (p2.z > v) { v = p2.z; ix = p2.w; }
      }
      const float xb = ix;
      const int rb = (uue << 2) << 8;
      const float s0 = sh[rb + b]              + sh[4096 + rb + b]
                     + sh[8192 + rb + b]       + sh[12288 + rb + b];
      const float s1 = sh[rb + 256 + b]        + sh[4096 + rb + 256 + b]
                     + sh[8192 + rb + 256 + b] + sh[12288 + rb + 256 + b];
      const float s2 = sh[rb + 512 + b]        + sh[4096 + rb + 512 + b]
                     + sh[8192 + rb + 512 + b] + sh[12288 + rb + 512 + b];
      const float s3 = sh[rb + 768 + b]        + sh[4096 + rb + 768 + b]
                     + sh[8192 + rb + 768 + b] + sh[12288 + rb + 768 + b];
      const float gi = s0 + bi_ + xb * wi_;
      const float gf = s1 + bf_ + xb * wf_;
      const float gg = s2 + bg_ + xb * wg_;
      const float go = s3 + bo_ + xb * wo_;
      const float co = cT[(ue << 8) + b];
      // accurate expf/tanhf: argmax feedback needs ~1e-6 accuracy
      const float cn = sigf(gf) * co + sigf(gi) * tanhf(gg);
      const float hn = sigf(go) * tanhf(cn);
      cT[(ue << 8) + b] = cn;
      hout[(blk << 10) + (b << 2) + uue] = hn;
    }
    gbar(bar);

    // ================= phase H: x_t = h @ w_lin^T + b_lin =================
    // stage h rows bc*16..+15 into sh[bb][u] (pad 1028 breaks bank conflicts)
#pragma unroll
    for (int i = 0; i < 8; ++i) {
      int idx = (i << 9) + tid;       // 0..4095
      int q = idx >> 4, bb = idx & 15;
      *(float4*)(&sh[bb * 1028 + (q << 2)]) =
          *(const float4*)(hout + (q << 10) + (((bc << 4) + bb) << 2));
    }
    __syncthreads();

    // wave wid covers u in [wid*128, wid*128+128) for 8 b's x its o
    float pa[8];
#pragma unroll
    for (int pp = 0; pp < 8; ++pp) pa[pp] = 0.f;
    const float* hpH = &sh[hb * 1028 + (wid << 7)];
#pragma unroll 4
    for (int ug = 0; ug < 32; ++ug) {
      const float4 wv = *(const float4*)(wpH + (ug << 11));
#pragma unroll
      for (int pp = 0; pp < 8; ++pp) {
        const float4 hv = *(const float4*)(hpH + pp * 1028 + (ug << 2));
        FMA4(pa[pp], wv, hv);
      }
    }
#pragma unroll
    for (int pp = 0; pp < 8; ++pp)
      xpart[(wid << 9) + ((hb + pp) << 5) + (lane & 31)] = pa[pp];
    __syncthreads();

    float a = 0.f;
#pragma unroll
    for (int ww = 0; ww < 8; ++ww) a += xpart[(ww << 9) + tid];
    a += blr;
    outp[t << 9] = a;

    // argmax over this 32-o chunk (strict >, min-index on ties => first max)
    float v = a, io = (float)oo;
#pragma unroll
    for (int m = 16; m >= 1; m >>= 1) {
      const float vo = __shfl_xor(v, m, 64);
      const float ioo = __shfl_xor(io, m, 64);
      if (vo > v || (vo == v && ioo < io)) { v = vo; io = ioo; }
    }
    if ((tid & 31) == 0)
      *(float2*)(part + (ob << 5) + (oc << 1)) = make_float2(v, io);
    gbar(bar);
  }
}

extern "C" void kernel_launch(void* const* d_in, const int* in_sizes, int n_in,
                              void* d_out, int out_size, void* d_ws, size_t ws_size,
                              hipStream_t stream) {
  (void)in_sizes; (void)n_in; (void)out_size; (void)ws_size;
  const float* z     = (const float*)d_in[0];
  const float* w_ih  = (const float*)d_in[1];
  const float* w_hh  = (const float*)d_in[2];
  const float* b_ih  = (const float*)d_in[3];
  const float* b_hh  = (const float*)d_in[4];
  const float* w_lin = (const float*)d_in[5];
  const float* b_lin = (const float*)d_in[6];
  float* out = (float*)d_out;
  float* ws  = (float*)d_ws;

  k_init<<<2048, 256, 0, stream>>>(z, w_lin, ws);

  void* args[] = {(void*)&w_hh, (void*)&w_ih, (void*)&b_ih, (void*)&b_hh,
                  (void*)&b_lin, (void*)&out, (void*)&ws};
  hipLaunchCooperativeKernel((const void*)k_persist, dim3(256), dim3(512),
                             args, 0, stream);
}

// Round 2
// 33297.861 us; speedup vs baseline: 1.4275x; 1.0873x over previous
//
#include <hip/hip_runtime.h>
#include <math.h>
#include <float.h>

// Problem: B=256, H=1024, I=1, O=512, T=512. Autoregressive LSTM + greedy head.
#define NB 256
#define NH 1024
#define NO 512
#define NT 512

// ---------------- workspace layout (float offsets) ----------------
// hT4 layout: [q=u>>2][b][j=u&3]  (256K floats per buffer)
#define OFF_HT4_0 0
#define OFF_HT4_1 (256*1024)
#define OFF_CT    (2*256*1024)            // cT [u][b]
#define OFF_WLT   (3*256*1024)            // packed w_lin: [u/4][o][4] = 512K floats
#define OFF_PART  (OFF_WLT + 512*1024)    // argmax partials [B][16][{val,idx}] = 8192
#define OFF_BAR   (OFF_PART + 8192)       // barrier: cnt8 @ dword i*16, master @128, gen @160

__device__ __forceinline__ float sigf(float x) { return 1.f / (1.f + expf(-x)); }

#define FMA4(A, W, H4) \
  A = fmaf((W).x, (H4).x, A); A = fmaf((W).y, (H4).y, A); \
  A = fmaf((W).z, (H4).z, A); A = fmaf((W).w, (H4).w, A);

// ---------------------------------------------------------------------------
// Init: pack h0=z into hT4 ping, c=0, pack w_lin into [u/4][o][4], seed argmax
// partials to (-FLT_MAX, 0) so step 0 sees xin = 0, zero barrier state.
// ---------------------------------------------------------------------------
__global__ void k_init(const float* __restrict__ z, const float* __restrict__ w_lin,
                       float* __restrict__ ws) {
  int idx = blockIdx.x * 256 + threadIdx.x;
  if (idx < 512 * 1024) {                 // wltp[uq*2048 + o*4 + j] = w_lin[o][4uq+j]
    int j = idx & 3, o = (idx >> 2) & 511, uq = idx >> 11;
    ws[OFF_WLT + idx] = w_lin[o * 1024 + (uq << 2) + j];
  }
  if (idx < 256 * 1024) {                 // hT4[q][b][j] = z[b][4q+j]; cT = 0
    int q = idx >> 10, r = idx & 1023, b = r >> 2, j = r & 3;
    ws[OFF_HT4_0 + idx] = z[b * 1024 + (q << 2) + j];
    ws[OFF_CT + idx] = 0.f;
  }
  if (idx < 8192) ws[OFF_PART + idx] = (idx & 1) ? 0.f : -FLT_MAX;
  if (idx < 256) ((unsigned*)(ws + OFF_BAR))[idx] = 0u;
}

// ---------------------------------------------------------------------------
// Hierarchical device-scope grid barrier: 8 sub-counters (32 blocks each,
// separate cache lines) -> 1 master -> generation bump. Cuts the 256-way
// same-line RMW serialization of a flat counter. Release chain: acq_rel RMWs
// (arrive->leader->master->gen); spinners do acquire fence after observing
// the new generation.
// ---------------------------------------------------------------------------
__device__ __forceinline__ void gbar(unsigned* bar, int bid) {
  __syncthreads();
  if (threadIdx.x == 0) {
    unsigned* gen = bar + 160;
    unsigned g = __hip_atomic_load(gen, __ATOMIC_RELAXED, __HIP_MEMORY_SCOPE_AGENT);
    unsigned* c = bar + ((bid & 7) << 4);
    unsigned a = __hip_atomic_fetch_add(c, 1u, __ATOMIC_ACQ_REL, __HIP_MEMORY_SCOPE_AGENT);
    bool done = false;
    if (a == 31u) {
      __hip_atomic_store(c, 0u, __ATOMIC_RELAXED, __HIP_MEMORY_SCOPE_AGENT);
      unsigned m = __hip_atomic_fetch_add(bar + 128, 1u, __ATOMIC_ACQ_REL,
                                          __HIP_MEMORY_SCOPE_AGENT);
      if (m == 7u) {
        __hip_atomic_store(bar + 128, 0u, __ATOMIC_RELAXED, __HIP_MEMORY_SCOPE_AGENT);
        __hip_atomic_fetch_add(gen, 1u, __ATOMIC_RELEASE, __HIP_MEMORY_SCOPE_AGENT);
        done = true;
      }
    }
    if (!done) {
      while (__hip_atomic_load(gen, __ATOMIC_RELAXED, __HIP_MEMORY_SCOPE_AGENT) == g)
        __builtin_amdgcn_s_sleep(2);
    }
    __builtin_amdgcn_fence(__ATOMIC_ACQUIRE, "agent");
  }
  __syncthreads();
}

// ---------------------------------------------------------------------------
// Persistent kernel, 256 blocks x 1024 threads (16 waves, 4 waves/SIMD).
// Block owns units blk*4..+3; 16 w_hh gate rows resident in LDS (64KB,
// staged once). Per iteration t:
//   merged phase: head(t-1) [h-tile in LDS, k split 8-way over waves,
//                 LDS reduce, shfl argmax -> partials] THEN matmul(t)
//                 [wave (rg=unit, kh=k-quarter): 4 rows x 4 b-cols x 256 k,
//                 h prefetch double-buffered from global]. Head's LDS-bound
//                 work fills matmul's memory-stall cycles; both read the
//                 SAME h(t-1), so L1/L2 locality compounds.
//   gbar -> epilogue: k-quarter partials summed from LDS, argmax(t-1)
//                 combined, LSTM cell update (1 (u,b) per thread), h write
//                 fully coalesced -> gbar.
// ---------------------------------------------------------------------------
__global__ __launch_bounds__(1024, 4) void k_persist(
    const float* __restrict__ w_hh, const float* __restrict__ w_ih,
    const float* __restrict__ b_ih, const float* __restrict__ b_hh,
    const float* __restrict__ b_lin, float* __restrict__ out,
    float* __restrict__ ws) {
  __shared__ float wlds[16 * 1024];   // resident w_hh rows (64 KB)
  __shared__ float sh[16 * 1028];     // head h-tile / matmul k-split exchange
  __shared__ float xpart[8 * 512];    // head k-split output partials (16 KB)

  const int tid = threadIdx.x;
  const int blk = blockIdx.x;
  const int lane = tid & 63;
  const int wid = tid >> 6;           // wave 0..15

  // matmul mapping: wave = (kh = k-quarter, rg = unit-within-quad)
  const int rg = wid & 3;
  const int kh = wid >> 2;

  // head mapping: block = (bc = blk>>4 -> 16 batches, oc = blk&15 -> 32 o's)
  // wave = (kh8 = k-eighth, bh = batch-half); lane = (bs = b-sub, ol = o)
  const int oc = blk & 15, bc = blk >> 4;
  const int kh8 = wid & 7, bh = wid >> 3;
  const int ol = lane & 31, bs = lane >> 5;

  unsigned* bar = (unsigned*)(ws + OFF_BAR);
  float* part = ws + OFF_PART;
  float* cT = ws + OFF_CT;
  const float* wlt = ws + OFF_WLT;

  // ---- one-time: stage 16 w_hh rows (row r=uu*4+g <-> global g*1024+blk*4+uu)
#pragma unroll
  for (int i = 0; i < 4; ++i) {
    int idx = (i << 10) + tid;        // 0..4095 float4s
    int r = idx >> 8, c4 = idx & 255;
    int grow = ((r & 3) << 10) + (blk << 2) + (r >> 2);
    *(float4*)(&wlds[(r << 10) + (c4 << 2)]) =
        *(const float4*)(w_hh + (grow << 10) + (c4 << 2));
  }

  // ---- epilogue constants: thread owns (unit uue, batch be); mapping chosen
  // so the h-state write is hnext[blk*1024 + tid] (fully coalesced).
  const int uue = tid & 3;
  const int be = tid >> 2;
  const int ue = (blk << 2) + uue;
  const float bi_ = b_ih[ue] + b_hh[ue];
  const float bf_ = b_ih[1024 + ue] + b_hh[1024 + ue];
  const float bg_ = b_ih[2048 + ue] + b_hh[2048 + ue];
  const float bo_ = b_ih[3072 + ue] + b_hh[3072 + ue];
  const float wi_ = w_ih[ue], wf_ = w_ih[1024 + ue];
  const float wg_ = w_ih[2048 + ue], wo_ = w_ih[3072 + ue];

  // ---- head constants
  const int oo = (oc << 5) + (tid & 31);       // reduce-mapping o (tid<512)
  const int ob = (bc << 4) + (tid >> 5);       // reduce-mapping b (tid<512)
  const float blr = b_lin[(oc << 5) + (tid & 31)];
  float* outp = out + (long)ob * (NT * NO) + oo;
  const float* wpH = wlt + ((kh8 << 5) << 11) + (((oc << 5) + ol) << 2);
  const float* hpH = &sh[((bh << 3) + (bs << 2)) * 1028 + (kh8 << 7)];

  __syncthreads();

  // head(t-1): x_{t-1} = h(t-1) @ w_lin^T + b_lin, argmax partials
  auto head_phase = [&](const float* __restrict__ hprev, int tout) {
    // stage h rows bc*16..+15 into sh[bb][u] (pad 1028 breaks conflicts)
#pragma unroll
    for (int i = 0; i < 4; ++i) {
      int idx = (i << 10) + tid;      // 0..4095
      int q = idx >> 4, bb = idx & 15;
      *(float4*)(&sh[bb * 1028 + (q << 2)]) =
          *(const float4*)(hprev + (q << 10) + (((bc << 4) + bb) << 2));
    }
    __syncthreads();
    float pa[4] = {0.f, 0.f, 0.f, 0.f};
#pragma unroll 4
    for (int ug = 0; ug < 32; ++ug) {
      const float4 wv = *(const float4*)(wpH + (ug << 11));
#pragma unroll
      for (int pp = 0; pp < 4; ++pp) {
        const float4 hv = *(const float4*)(hpH + pp * 1028 + (ug << 2));
        FMA4(pa[pp], wv, hv);
      }
    }
#pragma unroll
    for (int pp = 0; pp < 4; ++pp)
      xpart[(kh8 << 9) + (((bh << 3) + (bs << 2) + pp) << 5) + ol] = pa[pp];
    __syncthreads();
    if (tid < 512) {
      float a = blr;
#pragma unroll
      for (int kk = 0; kk < 8; ++kk) a += xpart[(kk << 9) + tid];
      outp[tout << 9] = a;
      // argmax over this 32-o chunk (strict >, min index on ties)
      float v = a, io = (float)oo;
#pragma unroll
      for (int m = 16; m >= 1; m >>= 1) {
        const float vo = __shfl_xor(v, m, 64);
        const float ioo = __shfl_xor(io, m, 64);
        if (vo > v || (vo == v && ioo < io)) { v = vo; io = ioo; }
      }
      if ((tid & 31) == 0)
        *(float2*)(part + (ob << 5) + (oc << 1)) = make_float2(v, io);
    }
  };

  for (int t = 0; t <= NT; ++t) {
    const float* hcur = ws + ((t & 1) ? OFF_HT4_1 : OFF_HT4_0);   // h(t-1)
    float* hnext = ws + ((t & 1) ? OFF_HT4_0 : OFF_HT4_1);        // h(t)

    if (t > 0) head_phase(hcur, t - 1);
    if (t == NT) break;

    // ================= matmul(t): gates = h(t-1) @ w_hh^T =================
    float acc[4][4];
#pragma unroll
    for (int j = 0; j < 4; ++j)
#pragma unroll
      for (int bb = 0; bb < 4; ++bb) acc[j][bb] = 0.f;
    {
      const float* hq = hcur + (kh << 16) + (lane << 2);
      const float* wb = &wlds[((rg << 2) << 10) + (kh << 8)];
      float4 hA[4], hB[4];
#pragma unroll
      for (int bb = 0; bb < 4; ++bb) hA[bb] = *(const float4*)(hq + (bb << 8));
      for (int qg = 0; qg < 64; qg += 2) {
        if ((qg & 7) == 0) __builtin_amdgcn_s_barrier();  // lockstep -> L1 reuse
#pragma unroll
        for (int bb = 0; bb < 4; ++bb)
          hB[bb] = *(const float4*)(hq + ((qg + 1) << 10) + (bb << 8));
#pragma unroll
        for (int j = 0; j < 4; ++j) {
          const float4 wv = *(const float4*)(wb + (j << 10) + (qg << 2));
#pragma unroll
          for (int bb = 0; bb < 4; ++bb) { FMA4(acc[j][bb], wv, hA[bb]); }
        }
        if (qg + 2 < 64) {
#pragma unroll
          for (int bb = 0; bb < 4; ++bb)
            hA[bb] = *(const float4*)(hq + ((qg + 2) << 10) + (bb << 8));
        }
#pragma unroll
        for (int j = 0; j < 4; ++j) {
          const float4 wv = *(const float4*)(wb + (j << 10) + ((qg + 1) << 2));
#pragma unroll
          for (int bb = 0; bb < 4; ++bb) { FMA4(acc[j][bb], wv, hB[bb]); }
        }
      }
    }
    // k-quarter partial exchange: sh[kh][row=rg*4+j][b]
#pragma unroll
    for (int j = 0; j < 4; ++j)
#pragma unroll
      for (int bb = 0; bb < 4; ++bb)
        sh[(kh << 12) + (((rg << 2) + j) << 8) + (bb << 6) + lane] = acc[j][bb];

    gbar(bar, blk);

    // ================= epilogue(t): LSTM cell update =================
    {
      // combine 16 argmax partials (ascending o-chunk, strict > => first wins)
      const float* pb = part + (be << 5);
      float4 p0 = *(const float4*)(pb);
      float v = p0.x, ix = p0.y;
      if (p0.z > v) { v = p0.z; ix = p0.w; }
#pragma unroll
      for (int cc = 1; cc < 8; ++cc) {
        float4 p2 = *(const float4*)(pb + (cc << 2));
        if (p2.x > v) { v = p2.x; ix = p2.y; }
        if (p2.z > v) { v = p2.z; ix = p2.w; }
      }
      const float xb = ix;
      const int rb = uue << 10;       // uue*4 rows * 256
      float s0 = 0.f, s1 = 0.f, s2 = 0.f, s3 = 0.f;
#pragma unroll
      for (int kk = 0; kk < 4; ++kk) {
        const int base = (kk << 12) + rb + be;
        s0 += sh[base];
        s1 += sh[base + 256];
        s2 += sh[base + 512];
        s3 += sh[base + 768];
      }
      const float gi = s0 + bi_ + xb * wi_;
      const float gf = s1 + bf_ + xb * wf_;
      const float gg = s2 + bg_ + xb * wg_;
      const float go = s3 + bo_ + xb * wo_;
      const float co = cT[(ue << 8) + be];
      // accurate expf/tanhf: argmax feedback needs ~1e-6 accuracy
      const float cn = sigf(gf) * co + sigf(gi) * tanhf(gg);
      const float hn = sigf(go) * tanhf(cn);
      cT[(ue << 8) + be] = cn;
      hnext[(blk << 10) + tid] = hn;  // = (be<<2)+uue: fully coalesced
    }
    gbar(bar, blk);
  }
}

extern "C" void kernel_launch(void* const* d_in, const int* in_sizes, int n_in,
                              void* d_out, int out_size, void* d_ws, size_t ws_size,
                              hipStream_t stream) {
  (void)in_sizes; (void)n_in; (void)out_size; (void)ws_size;
  const float* z     = (const float*)d_in[0];
  const float* w_ih  = (const float*)d_in[1];
  const float* w_hh  = (const float*)d_in[2];
  const float* b_ih  = (const float*)d_in[3];
  const float* b_hh  = (const float*)d_in[4];
  const float* w_lin = (const float*)d_in[5];
  const float* b_lin = (const float*)d_in[6];
  float* out = (float*)d_out;
  float* ws  = (float*)d_ws;

  k_init<<<2048, 256, 0, stream>>>(z, w_lin, ws);

  void* args[] = {(void*)&w_hh, (void*)&w_ih, (void*)&b_ih, (void*)&b_hh,
                  (void*)&b_lin, (void*)&out, (void*)&ws};
  hipLaunchCooperativeKernel((const void*)k_persist, dim3(256), dim3(1024),
                             args, 0, stream);
}